// Round 9
// baseline (25.195 us; speedup 1.0000x reference)
//
#include <hip/hip_runtime.h>
#include <math.h>

#define N_BUS 127
#define BATCH 4096
#define NUM_CS 200
#define STATE_DIM 858   // 4 + 2*127 + 3*200
#define EV_START 258    // 4 + 2*127
#define COLS 16         // batch columns per block -> 256 blocks of 512 threads
#define NITER 5         // contraction ~0.015: iter-5 error ~1e-9 << bf16 noise

typedef __attribute__((ext_vector_type(8))) short short8;
typedef __attribute__((ext_vector_type(4))) short short4v;
typedef __attribute__((ext_vector_type(4))) float f32x4;

// RNE float -> bf16
static __device__ __forceinline__ short f2bf(float f) {
    unsigned u = __float_as_uint(f);
    return (short)((u + 0x7FFFu + ((u >> 16) & 1u)) >> 16);
}

// 8 waves x 512 threads. Wave w owns output rows [16w, 16w+16).
// MFMA 16x16x32 fragment roles (layout verified rounds 3-7):
//   A: row = 16w + (l&15), k = 32kt + 8*(l>>4) + i
//   B: col = l&15,         k = 32kt + 8*(l>>4) + i
//   D: col = l&15,         row = 16w + 4*(l>>4) + r
__global__ __launch_bounds__(512, 4) void vvl_main(const float* __restrict__ action,
                                                   const float* __restrict__ state,
                                                   const float2* __restrict__ K,
                                                   const float2* __restrict__ Lp,
                                                   float* __restrict__ out) {
    __shared__ float2 kst[8][512];        // per-wave K chunk buffer (uses 508)
    __shared__ float  sq[COLS][258];      // [col]: p (EV added in) then q
    // B fragments, lane-linear: reader byte addr = const + 16*lane (conflict-free)
    __shared__ __align__(16) short B8s[2][2][4][4][COLS][8];
    __shared__ float lossred[COLS];

    const int tid = threadIdx.x;
    const int w  = tid >> 6;         // wave 0..7
    const int l  = tid & 63;
    const int cc = l & 15;           // batch column within tile
    const int g  = l >> 4;           // lane group 0..3
    const int b0 = blockIdx.x * COLS;
    const int col = tid >> 5;        // prologue column mapping (32 thr/col)
    const int j   = tid & 31;

    const float*  st_row_c = state + (size_t)(b0 + col) * STATE_DIM;
    const float2* st2      = (const float2*)(st_row_c + 4);
    const float*  act_row  = action + (size_t)(b0 + col) * NUM_CS;

    // ---- issue pq + EV global loads up front (independent, overlapped) ----
    float2 pqv[4];
    #pragma unroll
    for (int jj = 0; jj < 4; ++jj) {
        int idx = j + 32 * jj; idx = idx < 127 ? idx : 126;
        pqv[jj] = st2[idx];
    }
    float av[7], capv[7], busv[7];
    #pragma unroll
    for (int kk = 0; kk < 7; ++kk) {
        int cs = j + 32 * kk; int csc = cs < NUM_CS ? cs : NUM_CS - 1;
        av[kk]   = act_row[csc];
        capv[kk] = st_row_c[EV_START + 3 * csc];
        busv[kk] = st_row_c[EV_START + 2 + 3 * csc];
    }

    if (tid < COLS) lossred[tid] = 0.0f;
    #pragma unroll
    for (int jj = 0; jj < 4; ++jj) {
        int idx = j + 32 * jj;
        if (idx < 127) *(float2*)&sq[col][2 * idx] = pqv[jj];
    }

    // ---- K chunk 0 loads: lane-consecutive float2, fully coalesced ----
    const int arow = 16 * w + (l & 15);
    const bool rok = arow < N_BUS;
    float2 kreg[8];
    {
        const int base_c = (16 * w) * N_BUS;   // rows 16w..16w+3, contiguous
        #pragma unroll
        for (int q = 0; q < 8; ++q) {
            int ci = base_c + l + 64 * q;
            ci = ci < N_BUS * N_BUS ? ci : N_BUS * N_BUS - 1;
            kreg[q] = K[ci];
        }
    }
    __syncthreads();   // pq staged

    // ---- EV power + scatter-add into staged p (sq region of LDS) ----
    #pragma unroll
    for (int kk = 0; kk < 7; ++kk) {
        int cs = j + 32 * kk;
        float cap  = capv[kk];
        float conn = (cap > 0.0f) ? 1.0f : 0.0f;
        float mch  = fminf(22.0f,  conn * (70.0f - cap) * 4.0f);  // /0.25 == *4
        float mds  = fmaxf(-22.0f, conn * (15.0f - cap) * 4.0f);
        float pw   = fmaxf(fminf(av[kk] * 22.17f, mch), mds);
        int bi = (int)busv[kk];
        bi = bi < 0 ? 0 : (bi > N_BUS - 1 ? N_BUS - 1 : bi);
        if (cs < NUM_CS) atomicAdd(&sq[col][bi], pw);
    }

    // ---- A-fragment build: 4 chunks of 4 rows through per-wave LDS buffer ----
    // No barriers: kst[w] is wave-private; DS ops complete in order per wave.
    short8 AKr[4], AKi[4];
    #pragma unroll
    for (int kt = 0; kt < 4; ++kt) {
        #pragma unroll
        for (int i = 0; i < 8; ++i) { AKr[kt][i] = 0; AKi[kt][i] = 0; }
    }
    #pragma unroll
    for (int ch = 0; ch < 4; ++ch) {
        // write chunk ch (508 complex, linear)
        #pragma unroll
        for (int q = 0; q < 8; ++q) {
            int local = l + 64 * q;
            if (local < 508) kst[w][local] = kreg[q];
        }
        // prefetch chunk ch+1 while reading chunk ch
        float2 kreg2[8];
        if (ch < 3) {
            const int base_c = (16 * w + 4 * (ch + 1)) * N_BUS;
            #pragma unroll
            for (int q = 0; q < 8; ++q) {
                int ci = base_c + l + 64 * q;
                ci = ci < N_BUS * N_BUS ? ci : N_BUS * N_BUS - 1;
                kreg2[q] = K[ci];
            }
        }
        // fragment reads for the lanes whose row lives in this chunk
        const int ric  = (l & 15) - 4 * ch;                 // row in chunk
        const bool use = (ric >= 0) && (ric < 4) && rok;
        const int rbase = (use ? ric : 0) * N_BUS;
        #pragma unroll
        for (int kt = 0; kt < 4; ++kt) {
            #pragma unroll
            for (int i = 0; i < 8; ++i) {
                int k = 32 * kt + 8 * g + i;
                float2 e = kst[w][rbase + (k < N_BUS ? k : 0)];
                if (use && (k < N_BUS)) {
                    AKr[kt][i] = f2bf(e.x);
                    AKi[kt][i] = f2bf(e.y);
                }
            }
        }
        if (ch < 3) {
            #pragma unroll
            for (int q = 0; q < 8; ++q) kreg[q] = kreg2[q];
        }
    }
    __syncthreads();   // sq final (atomics done)

    // ---- per-lane S/v state from LDS ----
    float Sr[4], Si[4], lmr[4], lmi[4], vr[4], vi[4];
    #pragma unroll
    for (int r = 0; r < 4; ++r) {
        int row = 16 * w + 4 * g + r;
        if (row < N_BUS) {
            Sr[r] = sq[cc][row] * 1e-3f;
            Si[r] = sq[cc][127 + row] * 1e-3f;
            float2 lp = Lp[row];
            lmr[r] = lp.x; lmi[r] = lp.y;
        } else {  // pad row 127: S=0 -> Lc=0; A col 127 is zero anyway
            Sr[r] = 0.0f; Si[r] = 0.0f; lmr[r] = 1.0f; lmi[r] = 0.0f;
        }
        vr[r] = 1.0f; vi[r] = 0.0f;
    }

    // writer-side B8 constants: this lane owns k = k0..k0+3 of column cc
    const int k0  = 16 * w + 4 * g;
    const int ktw = k0 >> 5;
    const int gi  = (k0 >> 3) & 3;
    const int i0  = k0 & 7;          // 0 or 4

    // ---- fixed-point loop: v = K @ conj(S/v) + L on matrix cores ----
    for (int it = 0; it < NITER; ++it) {
        const int buf = it & 1;
        short4v pr, pi;
        #pragma unroll
        for (int r = 0; r < 4; ++r) {
            float d   = vr[r] * vr[r] + vi[r] * vi[r];
            float inv = __builtin_amdgcn_rcpf(d);
            pr[r] = f2bf((Sr[r] * vr[r] + Si[r] * vi[r]) * inv);
            pi[r] = f2bf((Sr[r] * vi[r] - Si[r] * vr[r]) * inv);
        }
        *(short4v*)&B8s[buf][0][ktw][gi][cc][i0] = pr;
        *(short4v*)&B8s[buf][1][ktw][gi][cc][i0] = pi;
        __syncthreads();   // single barrier/iter; WAR safe via double buffer

        // Cre = Kr@Lr + Ki@(-Li) ; Cim = Kr@Li + Ki@Lr   (fp32 accum)
        f32x4 are = {0.f, 0.f, 0.f, 0.f}, aim = {0.f, 0.f, 0.f, 0.f};
        #pragma unroll
        for (int kt = 0; kt < 4; ++kt) {
            short8 Br  = *(const short8*)&B8s[buf][0][kt][g][cc][0];
            short8 Bi8 = *(const short8*)&B8s[buf][1][kt][g][cc][0];
            aim = __builtin_amdgcn_mfma_f32_16x16x32_bf16(AKr[kt], Bi8, aim, 0, 0, 0);
            aim = __builtin_amdgcn_mfma_f32_16x16x32_bf16(AKi[kt], Br,  aim, 0, 0, 0);
            are = __builtin_amdgcn_mfma_f32_16x16x32_bf16(AKr[kt], Br,  are, 0, 0, 0);
            #pragma unroll
            for (int i = 0; i < 8; ++i) Bi8[i] = Bi8[i] ^ (short)0x8000;   // -Li
            are = __builtin_amdgcn_mfma_f32_16x16x32_bf16(AKi[kt], Bi8, are, 0, 0, 0);
        }
        #pragma unroll
        for (int r = 0; r < 4; ++r) {
            vr[r] = are[r] + lmr[r];
            vi[r] = aim[r] + lmi[r];
        }
    }

    // ---- loss = 1000 * sum_n min(0, 0.05 - |1 - |v||) per column ----
    float ls = 0.0f;
    #pragma unroll
    for (int r = 0; r < 4; ++r) {
        int row = 16 * w + 4 * g + r;
        if (row < N_BUS) {
            float na = sqrtf(vr[r] * vr[r] + vi[r] * vi[r]);
            ls += fminf(0.0f, 0.05f - fabsf(1.0f - na));
        }
    }
    // reduce over the 4 lane-groups sharing column cc within this wave
    ls += __shfl_xor(ls, 16);
    ls += __shfl_xor(ls, 32);
    if (g == 0) atomicAdd(&lossred[cc], ls);   // 8 waves -> block total
    __syncthreads();
    if (tid < COLS) out[b0 + tid] = 1000.0f * lossred[tid];
}

extern "C" void kernel_launch(void* const* d_in, const int* in_sizes, int n_in,
                              void* d_out, int out_size, void* d_ws, size_t ws_size,
                              hipStream_t stream) {
    const float*  action = (const float*)d_in[0];
    const float*  state  = (const float*)d_in[1];
    const float2* K      = (const float2*)d_in[2];
    const float2* Lp     = (const float2*)d_in[3];
    float* out = (float*)d_out;

    vvl_main<<<BATCH / COLS, 512, 0, stream>>>(action, state, K, Lp, out);
}

// Round 10
// 20.045 us; speedup vs baseline: 1.2569x; 1.2569x over previous
//
#include <hip/hip_runtime.h>
#include <math.h>

#define N_BUS 127
#define BATCH 4096
#define NUM_CS 200
#define STATE_DIM 858   // 4 + 2*127 + 3*200
#define EV_START 258    // 4 + 2*127
#define COLS 8          // batch columns per block -> 512 blocks, 2 blocks/CU
#define NITER 5         // contraction ~0.015: iter-5 error ~1e-9 << bf16 noise

typedef __attribute__((ext_vector_type(8))) short short8;
typedef __attribute__((ext_vector_type(4))) short short4v;
typedef __attribute__((ext_vector_type(4))) float f32x4;

// RNE float -> bf16
static __device__ __forceinline__ short f2bf(float f) {
    unsigned u = __float_as_uint(f);
    return (short)((u + 0x7FFFu + ((u >> 16) & 1u)) >> 16);
}

// 8 waves x 512 threads. Wave w owns output rows [16w, 16w+16).
// MFMA 16x16x32 fragment roles (layout verified rounds 3-9):
//   A: row = 16w + (l&15), k = 32kt + 8*(l>>4) + i
//   B: col = l&15,         k = 32kt + 8*(l>>4) + i
//   D: col = l&15,         row = 16w + 4*(l>>4) + r
// B-columns 8..15 duplicate 0..7 (COLS=8): MFMA slots are cheap, TLP is not.
__global__ __launch_bounds__(512, 4) void vvl_main(const float* __restrict__ action,
                                                   const float* __restrict__ state,
                                                   const float2* __restrict__ K,
                                                   const float2* __restrict__ Lp,
                                                   float* __restrict__ out) {
    __shared__ float sq[COLS][258];      // [col]: p (EV added in) then q
    // B fragments, lane-linear: reader byte addr = const + 16*lane (conflict-free)
    __shared__ __align__(16) short B8s[2][2][4][4][16][8];
    __shared__ float lossred[16];

    const int tid = threadIdx.x;
    const int w  = tid >> 6;         // wave 0..7
    const int l  = tid & 63;
    const int cc = l & 15;           // B-column slot; data column = cc&7
    const int c8 = cc & 7;
    const int g  = l >> 4;           // lane group 0..3
    const int b0 = blockIdx.x * COLS;
    const int col = tid >> 6;        // prologue column mapping (64 thr/col)
    const int j   = tid & 63;

    const float*  st_row_c = state + (size_t)(b0 + col) * STATE_DIM;
    const float2* st2      = (const float2*)(st_row_c + 4);
    const float*  act_row  = action + (size_t)(b0 + col) * NUM_CS;

    // ---- batch 1: p/q loads (consumed first; in-order VMEM return) ----
    float2 pqv[2];
    #pragma unroll
    for (int jj = 0; jj < 2; ++jj) {
        int idx = j + 64 * jj; idx = idx < 127 ? idx : 126;
        pqv[jj] = st2[idx];
    }
    // ---- batch 2: EV loads (12 independent scalars, uniform trip count) ----
    float av[4], capv[4], busv[4];
    #pragma unroll
    for (int kk = 0; kk < 4; ++kk) {
        int cs = j + 64 * kk; int csc = cs < NUM_CS ? cs : NUM_CS - 1;
        av[kk]   = act_row[csc];
        capv[kk] = st_row_c[EV_START + 3 * csc];
        busv[kk] = st_row_c[EV_START + 2 + 3 * csc];
    }
    // ---- batch 3: K first half (kt 0,1); row gather L1-resident ----
    const int arow = 16 * w + (l & 15);
    const bool rok = arow < N_BUS;
    const float2* Krow = K + (size_t)(rok ? arow : 0) * N_BUS;
    float2 k1[16];
    #pragma unroll
    for (int kt = 0; kt < 2; ++kt)
        #pragma unroll
        for (int i = 0; i < 8; ++i) {
            int k = 32 * kt + 8 * g + i;
            k1[kt * 8 + i] = Krow[k < N_BUS ? k : 0];
        }

    if (tid < 16) lossred[tid] = 0.0f;
    // store pq (waits on batch 1 only; EV/K still in flight)
    #pragma unroll
    for (int jj = 0; jj < 2; ++jj) {
        int idx = j + 64 * jj;
        if (idx < 127) *(float2*)&sq[col][2 * idx] = pqv[jj];
    }
    __syncthreads();

    // ---- EV power + scatter-add into staged p ----
    #pragma unroll
    for (int kk = 0; kk < 4; ++kk) {
        int cs = j + 64 * kk;
        float cap  = capv[kk];
        float conn = (cap > 0.0f) ? 1.0f : 0.0f;
        float mch  = fminf(22.0f,  conn * (70.0f - cap) * 4.0f);  // /0.25 == *4
        float mds  = fmaxf(-22.0f, conn * (15.0f - cap) * 4.0f);
        float pw   = fmaxf(fminf(av[kk] * 22.17f, mch), mds);
        int bi = (int)busv[kk];
        bi = bi < 0 ? 0 : (bi > N_BUS - 1 ? N_BUS - 1 : bi);
        if (cs < NUM_CS) atomicAdd(&sq[col][bi], pw);
    }

    // ---- batch 4: K second half (latency hides under K1 convert) ----
    float2 k2[16];
    #pragma unroll
    for (int kt = 2; kt < 4; ++kt)
        #pragma unroll
        for (int i = 0; i < 8; ++i) {
            int k = 32 * kt + 8 * g + i;
            k2[(kt - 2) * 8 + i] = Krow[k < N_BUS ? k : 0];
        }

    // convert K1 -> bf16 A-fragments while K2 is in flight
    short8 AKr[4], AKi[4];
    #pragma unroll
    for (int kt = 0; kt < 2; ++kt)
        #pragma unroll
        for (int i = 0; i < 8; ++i) {
            int k = 32 * kt + 8 * g + i;
            bool ok = rok && (k < N_BUS);
            float2 e = k1[kt * 8 + i];
            AKr[kt][i] = f2bf(ok ? e.x : 0.0f);
            AKi[kt][i] = f2bf(ok ? e.y : 0.0f);
        }

    __syncthreads();   // sq final (atomics done)

    // ---- per-lane S/v state from LDS ----
    float Sr[4], Si[4], lmr[4], lmi[4], vr[4], vi[4];
    #pragma unroll
    for (int r = 0; r < 4; ++r) {
        int row = 16 * w + 4 * g + r;
        if (row < N_BUS) {
            Sr[r] = sq[c8][row] * 1e-3f;
            Si[r] = sq[c8][127 + row] * 1e-3f;
            float2 lp = Lp[row];
            lmr[r] = lp.x; lmi[r] = lp.y;
        } else {  // pad row 127: S=0 -> Lc=0; A col 127 is zero anyway
            Sr[r] = 0.0f; Si[r] = 0.0f; lmr[r] = 1.0f; lmi[r] = 0.0f;
        }
        vr[r] = 1.0f; vi[r] = 0.0f;
    }

    // convert K2
    #pragma unroll
    for (int kt = 2; kt < 4; ++kt)
        #pragma unroll
        for (int i = 0; i < 8; ++i) {
            int k = 32 * kt + 8 * g + i;
            bool ok = rok && (k < N_BUS);
            float2 e = k2[(kt - 2) * 8 + i];
            AKr[kt][i] = f2bf(ok ? e.x : 0.0f);
            AKi[kt][i] = f2bf(ok ? e.y : 0.0f);
        }

    // writer-side B8 constants: this lane owns k = k0..k0+3 of column cc
    const int k0  = 16 * w + 4 * g;
    const int ktw = k0 >> 5;
    const int gi  = (k0 >> 3) & 3;
    const int i0  = k0 & 7;          // 0 or 4

    // ---- fixed-point loop: v = K @ conj(S/v) + L on matrix cores ----
    for (int it = 0; it < NITER; ++it) {
        const int buf = it & 1;
        short4v pr, pi;
        #pragma unroll
        for (int r = 0; r < 4; ++r) {
            float d   = vr[r] * vr[r] + vi[r] * vi[r];
            float inv = __builtin_amdgcn_rcpf(d);
            pr[r] = f2bf((Sr[r] * vr[r] + Si[r] * vi[r]) * inv);
            pi[r] = f2bf((Sr[r] * vi[r] - Si[r] * vr[r]) * inv);
        }
        *(short4v*)&B8s[buf][0][ktw][gi][cc][i0] = pr;
        *(short4v*)&B8s[buf][1][ktw][gi][cc][i0] = pi;
        __syncthreads();   // single barrier/iter; WAR safe via double buffer

        // Cre = Kr@Lr + Ki@(-Li) ; Cim = Kr@Li + Ki@Lr   (fp32 accum)
        f32x4 are = {0.f, 0.f, 0.f, 0.f}, aim = {0.f, 0.f, 0.f, 0.f};
        #pragma unroll
        for (int kt = 0; kt < 4; ++kt) {
            short8 Br  = *(const short8*)&B8s[buf][0][kt][g][cc][0];
            short8 Bi8 = *(const short8*)&B8s[buf][1][kt][g][cc][0];
            aim = __builtin_amdgcn_mfma_f32_16x16x32_bf16(AKr[kt], Bi8, aim, 0, 0, 0);
            aim = __builtin_amdgcn_mfma_f32_16x16x32_bf16(AKi[kt], Br,  aim, 0, 0, 0);
            are = __builtin_amdgcn_mfma_f32_16x16x32_bf16(AKr[kt], Br,  are, 0, 0, 0);
            #pragma unroll
            for (int i = 0; i < 8; ++i) Bi8[i] = Bi8[i] ^ (short)0x8000;   // -Li
            are = __builtin_amdgcn_mfma_f32_16x16x32_bf16(AKi[kt], Bi8, are, 0, 0, 0);
        }
        #pragma unroll
        for (int r = 0; r < 4; ++r) {
            vr[r] = are[r] + lmr[r];
            vi[r] = aim[r] + lmi[r];
        }
    }

    // ---- loss = 1000 * sum_n min(0, 0.05 - |1 - |v||) per column ----
    float ls = 0.0f;
    #pragma unroll
    for (int r = 0; r < 4; ++r) {
        int row = 16 * w + 4 * g + r;
        if (row < N_BUS) {
            float na = sqrtf(vr[r] * vr[r] + vi[r] * vi[r]);
            ls += fminf(0.0f, 0.05f - fabsf(1.0f - na));
        }
    }
    // reduce over the 4 lane-groups sharing column cc within this wave
    ls += __shfl_xor(ls, 16);
    ls += __shfl_xor(ls, 32);
    if (g == 0 && cc < COLS) atomicAdd(&lossred[cc], ls);   // 8 waves -> total
    __syncthreads();
    if (tid < COLS) out[b0 + tid] = 1000.0f * lossred[tid];
}

extern "C" void kernel_launch(void* const* d_in, const int* in_sizes, int n_in,
                              void* d_out, int out_size, void* d_ws, size_t ws_size,
                              hipStream_t stream) {
    const float*  action = (const float*)d_in[0];
    const float*  state  = (const float*)d_in[1];
    const float2* K      = (const float2*)d_in[2];
    const float2* Lp     = (const float2*)d_in[3];
    float* out = (float*)d_out;

    vvl_main<<<BATCH / COLS, 512, 0, stream>>>(action, state, K, Lp, out);
}

// Round 11
// 17.959 us; speedup vs baseline: 1.4029x; 1.1161x over previous
//
#include <hip/hip_runtime.h>
#include <math.h>

#define N_BUS 127
#define BATCH 4096
#define NUM_CS 200
#define STATE_DIM 858   // 4 + 2*127 + 3*200
#define EV_START 258    // 4 + 2*127
#define COLS 16         // batch columns per block -> 256 blocks of 512 threads
#define NITER 5         // contraction: iter-5 error ~8e-6 << 0.03 dead-band margin

typedef __attribute__((ext_vector_type(8))) short short8;
typedef __attribute__((ext_vector_type(4))) short short4v;
typedef __attribute__((ext_vector_type(4))) float f32x4;

// RNE float -> bf16
static __device__ __forceinline__ short f2bf(float f) {
    unsigned u = __float_as_uint(f);
    return (short)((u + 0x7FFFu + ((u >> 16) & 1u)) >> 16);
}

// 8 waves x 512 threads. Wave w owns output rows [16w, 16w+16).
// MFMA 16x16x32 fragment roles (layout verified rounds 3-10):
//   A: row = 16w + (l&15), k = 32kt + 8*(l>>4) + i
//   B: col = l&15,         k = 32kt + 8*(l>>4) + i
//   D: col = l&15,         row = 16w + 4*(l>>4) + r
// launch_bounds (512,2): 256-VGPR cap so ALL prologue loads stay in flight
// simultaneously (the (512,4)/128 cap forced load->wait->convert serialization:
// r9/r10 compiled to 52 VGPRs = ~30 sequential memory-latency hops ~ 11 us).
__global__ __launch_bounds__(512, 2) void vvl_main(const float* __restrict__ action,
                                                   const float* __restrict__ state,
                                                   const float2* __restrict__ K,
                                                   const float2* __restrict__ Lp,
                                                   float* __restrict__ out) {
    __shared__ float sq[COLS][258];      // [col]: p (EV added in) then q
    // B fragments, lane-linear: reader byte addr = const + 16*lane (conflict-free)
    __shared__ __align__(16) short B8s[2][2][4][4][COLS][8];
    __shared__ float lossred[COLS];

    const int tid = threadIdx.x;
    const int w  = tid >> 6;         // wave 0..7
    const int l  = tid & 63;
    const int cc = l & 15;           // batch column within tile
    const int g  = l >> 4;           // lane group 0..3
    const int b0 = blockIdx.x * COLS;
    const int col = tid >> 5;        // prologue column mapping (32 thr/col)
    const int j   = tid & 31;

    const float*  st_row_c = state + (size_t)(b0 + col) * STATE_DIM;
    const float2* st2      = (const float2*)(st_row_c + 4);
    const float*  act_row  = action + (size_t)(b0 + col) * NUM_CS;

    // ======= issue EVERY prologue load before any use (in-order VMEM) =======
    // batch 1: p/q (consumed first)
    float2 pqv[4];
    #pragma unroll
    for (int jj = 0; jj < 4; ++jj) {
        int idx = j + 32 * jj; idx = idx < 127 ? idx : 126;
        pqv[jj] = st2[idx];
    }
    // batch 2: EV (21 scalars)
    float av[7], capv[7], busv[7];
    #pragma unroll
    for (int kk = 0; kk < 7; ++kk) {
        int cs = j + 32 * kk; int csc = cs < NUM_CS ? cs : NUM_CS - 1;
        av[kk]   = act_row[csc];
        capv[kk] = st_row_c[EV_START + 3 * csc];
        busv[kk] = st_row_c[EV_START + 2 + 3 * csc];
    }
    // batch 3: all 32 K row-gather loads (L1 line reuse 8x within a lane)
    const int arow = 16 * w + (l & 15);
    const bool rok = arow < N_BUS;
    const float2* Krow = K + (size_t)(rok ? arow : 0) * N_BUS;
    float2 kv[32];
    #pragma unroll
    for (int kt = 0; kt < 4; ++kt)
        #pragma unroll
        for (int i = 0; i < 8; ++i) {
            int k = 32 * kt + 8 * g + i;
            kv[kt * 8 + i] = Krow[k < N_BUS ? k : 0];
        }

    if (tid < COLS) lossred[tid] = 0.0f;

    // ======= consume in issue order =======
    // pq -> LDS (waits only batch 1; EV + K stay in flight)
    #pragma unroll
    for (int jj = 0; jj < 4; ++jj) {
        int idx = j + 32 * jj;
        if (idx < 127) *(float2*)&sq[col][2 * idx] = pqv[jj];
    }
    __syncthreads();

    // EV power + scatter-add into staged p (waits batch 2; K still in flight)
    #pragma unroll
    for (int kk = 0; kk < 7; ++kk) {
        int cs = j + 32 * kk;
        float cap  = capv[kk];
        float conn = (cap > 0.0f) ? 1.0f : 0.0f;
        float mch  = fminf(22.0f,  conn * (70.0f - cap) * 4.0f);  // /0.25 == *4
        float mds  = fmaxf(-22.0f, conn * (15.0f - cap) * 4.0f);
        float pw   = fmaxf(fminf(av[kk] * 22.17f, mch), mds);
        int bi = (int)busv[kk];
        bi = bi < 0 ? 0 : (bi > N_BUS - 1 ? N_BUS - 1 : bi);
        if (cs < NUM_CS) atomicAdd(&sq[col][bi], pw);
    }

    // convert K -> bf16 A-fragments (single wait on batch 3)
    short8 AKr[4], AKi[4];
    #pragma unroll
    for (int kt = 0; kt < 4; ++kt)
        #pragma unroll
        for (int i = 0; i < 8; ++i) {
            int k = 32 * kt + 8 * g + i;
            bool ok = rok && (k < N_BUS);
            float2 e = kv[kt * 8 + i];
            AKr[kt][i] = f2bf(ok ? e.x : 0.0f);
            AKi[kt][i] = f2bf(ok ? e.y : 0.0f);
        }

    __syncthreads();   // sq final (atomics done)

    // ---- per-lane S/v state from LDS ----
    float Sr[4], Si[4], lmr[4], lmi[4], vr[4], vi[4];
    #pragma unroll
    for (int r = 0; r < 4; ++r) {
        int row = 16 * w + 4 * g + r;
        if (row < N_BUS) {
            Sr[r] = sq[cc][row] * 1e-3f;
            Si[r] = sq[cc][127 + row] * 1e-3f;
            float2 lp = Lp[row];
            lmr[r] = lp.x; lmi[r] = lp.y;
        } else {  // pad row 127: S=0 -> Lc=0; A col 127 is zero anyway
            Sr[r] = 0.0f; Si[r] = 0.0f; lmr[r] = 1.0f; lmi[r] = 0.0f;
        }
        vr[r] = 1.0f; vi[r] = 0.0f;
    }

    // writer-side B8 constants: this lane owns k = k0..k0+3 of column cc
    const int k0  = 16 * w + 4 * g;
    const int ktw = k0 >> 5;
    const int gi  = (k0 >> 3) & 3;
    const int i0  = k0 & 7;          // 0 or 4

    // ---- fixed-point loop: v = K @ conj(S/v) + L on matrix cores ----
    for (int it = 0; it < NITER; ++it) {
        const int buf = it & 1;
        short4v pr, pi;
        #pragma unroll
        for (int r = 0; r < 4; ++r) {
            float d   = vr[r] * vr[r] + vi[r] * vi[r];
            float inv = __builtin_amdgcn_rcpf(d);
            pr[r] = f2bf((Sr[r] * vr[r] + Si[r] * vi[r]) * inv);
            pi[r] = f2bf((Sr[r] * vi[r] - Si[r] * vr[r]) * inv);
        }
        *(short4v*)&B8s[buf][0][ktw][gi][cc][i0] = pr;
        *(short4v*)&B8s[buf][1][ktw][gi][cc][i0] = pi;
        __syncthreads();   // single barrier/iter; WAR safe via double buffer

        // Cre = Kr@Lr + Ki@(-Li) ; Cim = Kr@Li + Ki@Lr   (fp32 accum)
        f32x4 are = {0.f, 0.f, 0.f, 0.f}, aim = {0.f, 0.f, 0.f, 0.f};
        #pragma unroll
        for (int kt = 0; kt < 4; ++kt) {
            short8 Br  = *(const short8*)&B8s[buf][0][kt][g][cc][0];
            short8 Bi8 = *(const short8*)&B8s[buf][1][kt][g][cc][0];
            aim = __builtin_amdgcn_mfma_f32_16x16x32_bf16(AKr[kt], Bi8, aim, 0, 0, 0);
            aim = __builtin_amdgcn_mfma_f32_16x16x32_bf16(AKi[kt], Br,  aim, 0, 0, 0);
            are = __builtin_amdgcn_mfma_f32_16x16x32_bf16(AKr[kt], Br,  are, 0, 0, 0);
            #pragma unroll
            for (int i = 0; i < 8; ++i) Bi8[i] = Bi8[i] ^ (short)0x8000;   // -Li
            are = __builtin_amdgcn_mfma_f32_16x16x32_bf16(AKi[kt], Bi8, are, 0, 0, 0);
        }
        #pragma unroll
        for (int r = 0; r < 4; ++r) {
            vr[r] = are[r] + lmr[r];
            vi[r] = aim[r] + lmi[r];
        }
    }

    // ---- loss = 1000 * sum_n min(0, 0.05 - |1 - |v||) per column ----
    float ls = 0.0f;
    #pragma unroll
    for (int r = 0; r < 4; ++r) {
        int row = 16 * w + 4 * g + r;
        if (row < N_BUS) {
            float na = sqrtf(vr[r] * vr[r] + vi[r] * vi[r]);
            ls += fminf(0.0f, 0.05f - fabsf(1.0f - na));
        }
    }
    // reduce over the 4 lane-groups sharing column cc within this wave
    ls += __shfl_xor(ls, 16);
    ls += __shfl_xor(ls, 32);
    if (g == 0) atomicAdd(&lossred[cc], ls);   // 8 waves -> block total
    __syncthreads();
    if (tid < COLS) out[b0 + tid] = 1000.0f * lossred[tid];
}

extern "C" void kernel_launch(void* const* d_in, const int* in_sizes, int n_in,
                              void* d_out, int out_size, void* d_ws, size_t ws_size,
                              hipStream_t stream) {
    const float*  action = (const float*)d_in[0];
    const float*  state  = (const float*)d_in[1];
    const float2* K      = (const float2*)d_in[2];
    const float2* Lp     = (const float2*)d_in[3];
    float* out = (float*)d_out;

    vvl_main<<<BATCH / COLS, 512, 0, stream>>>(action, state, K, Lp, out);
}